// Round 4
// baseline (649.379 us; speedup 1.0000x reference)
//
#include <hip/hip_runtime.h>
#include <stdint.h>

#define BB 8
#define LL 2048
#define DD 1024
#define HH 1024
#define BL (BB*LL)   // 16384

typedef __attribute__((ext_vector_type(8))) short short8;
typedef __attribute__((ext_vector_type(4))) float f32x4;

__device__ __forceinline__ unsigned short f2bf(float f) {
  unsigned int x = __float_as_uint(f);
  unsigned int r = (x + 0x7fffu + ((x >> 16) & 1u)) >> 16;
  return (unsigned short)r;
}
__device__ __forceinline__ float bf2f(unsigned short u) {
  return __uint_as_float(((unsigned int)u) << 16);
}

__device__ __forceinline__ void stage16(const unsigned short* g, unsigned short* l) {
  __builtin_amdgcn_global_load_lds((const __attribute__((address_space(1))) void*)g,
                                   (__attribute__((address_space(3))) void*)l,
                                   16, 0, 0);
}

// ================= 4-phase-per-K-tile interleaved core (T3+T4+T5) =================
// 512 threads = 8 waves (2M x 4N), BM=BN=256, BK=64. LDS: 2 K-tile buffers
// (A 256x64 + B 256x64 each) = 128 KiB. Per K-tile, 4 phases; each phase:
//   { quadrant ds_reads (8-12 x b128) ; stage one half-class (2 x gload_lds) }
//   sched_barrier ; s_barrier ; lgkmcnt(0)+sched_barrier ; setprio(1) ;
//   16 MFMA ; setprio(0) ; sched_barrier ; s_barrier ; sched_barrier
// Half-classes (16 chunks of 8 rows each; wave w stages 2 consecutive chunks):
//   A0 = rows {0-63,128-191}   (per-wave m-frags 0-3)  last read ph3
//   A1 = rows {64-127,192-255} (m-frags 4-7)           last read ph4
//   B0 = rows {r:(r&63)<32}    (per-wave n-frags 0-1)  last read ph1 (regs reused ph2)
//   B1 = rows {r:(r&63)>=32}   (n-frags 2-3)           last read ph3
// Stage schedule in iter t: ph1 A1(t+1)->buf^1, ph2 B1(t+1)->buf^1,
//   ph3 B0(t+2)->buf (region dead after ph1), ph4 A0(t+2)->buf (dead after ph3).
// Every stage is issued after the bar2 following its target region's last reads.
// One counted vmcnt(4) per K-tile at ph4 (T4: never 0 mid-loop): drains exactly
// tile t+1's 4 half-classes (8 loads), leaves tile t+2's B0,A0 (4 loads) flying.
// Ledger: outstanding before wait = 4 (B0/A0 of t+1, staged ph3/ph4 of t-1)
//   + 8 (this iter) = 12 -> vmcnt(4) drains oldest 8 = all of tile t+1. QED.
// XOR-swizzle layout identical to the previously verified core (0 bank conflicts).
struct __align__(16) Smem8 {
  unsigned short a[2][16384];   // 256 x 64 per buffer
  unsigned short b[2][16384];
};
static_assert(sizeof(Smem8) == 131072, "LDS size");

__device__ __forceinline__ void acc_init8(f32x4 (&acc)[8][4]) {
#pragma unroll
  for (int i = 0; i < 8; ++i)
#pragma unroll
    for (int j = 0; j < 4; ++j)
      acc[i][j] = (f32x4){0.f, 0.f, 0.f, 0.f};
}

template<class FA, class FB>
__device__ __forceinline__ void gemm8_core(FA srcA, FB srcB, int NK,
                                           Smem8* sm, f32x4 (&acc)[8][4]) {
  const int lane = threadIdx.x & 63;
  const int wave = threadIdx.x >> 6;           // 0..7
  const int srow = lane >> 3;                  // 0..7
  const int scol = ((lane & 7) ^ srow) * 8;    // swizzled source column
  const int fk = (lane >> 4) * 8;
  const int fr = lane & 15;
  const int fx = fr & 7;
  const int mwr = (wave >> 2) * 128;           // wave row base
  const int nwr = (wave & 3) * 64;             // wave col base
  // per-wave chunk bases (2 consecutive chunks per class per wave)
  const int cA0 = (wave < 4) ? 2 * wave : 2 * wave + 8;   // {0-7,16-23}
  const int cA1 = cA0 + 8;                                 // {8-15,24-31}
  const int cB0 = (wave >> 1) * 8 + 2 * (wave & 1);        // {c:(c&7)<4}
  const int cB1 = cB0 + 4;                                 // {c:(c&7)>=4}

  auto SA = [&](int p, int kt, int c) {
    stage16(srcA(c * 8 + srow, kt) + scol, &sm->a[p][c * 512]);
    stage16(srcA(c * 8 + 8 + srow, kt) + scol, &sm->a[p][(c + 1) * 512]);
  };
  auto SB = [&](int p, int kt, int c) {
    stage16(srcB(c * 8 + srow, kt) + scol, &sm->b[p][c * 512]);
    stage16(srcB(c * 8 + 8 + srow, kt) + scol, &sm->b[p][(c + 1) * 512]);
  };
  short8 af[4][2], bfv[2][2];
  auto LDA = [&](int p, int ih) {
#pragma unroll
    for (int i = 0; i < 4; ++i)
#pragma unroll
      for (int kk = 0; kk < 2; ++kk) {
        const int kc = ((((kk * 32 + fk) >> 3) ^ fx) << 3);
        af[i][kk] = *(const short8*)&sm->a[p][(mwr + ih * 64 + i * 16 + fr) * 64 + kc];
      }
  };
  auto LDB = [&](int p, int jh) {
#pragma unroll
    for (int j = 0; j < 2; ++j)
#pragma unroll
      for (int kk = 0; kk < 2; ++kk) {
        const int kc = ((((kk * 32 + fk) >> 3) ^ fx) << 3);
        bfv[j][kk] = *(const short8*)&sm->b[p][(nwr + jh * 32 + j * 16 + fr) * 64 + kc];
      }
  };
  auto MM = [&](int ih, int jh) {
#pragma unroll
    for (int i = 0; i < 4; ++i)
#pragma unroll
      for (int j = 0; j < 2; ++j)
#pragma unroll
        for (int kk = 0; kk < 2; ++kk)
          acc[ih * 4 + i][jh * 2 + j] = __builtin_amdgcn_mfma_f32_16x16x32_bf16(
              af[i][kk], bfv[j][kk], acc[ih * 4 + i][jh * 2 + j], 0, 0, 0);
  };

#define PH(IH, JH, ...) do { \
    __VA_ARGS__ \
    __builtin_amdgcn_sched_barrier(0); \
    __builtin_amdgcn_s_barrier(); \
    asm volatile("s_waitcnt lgkmcnt(0)" ::: "memory"); \
    __builtin_amdgcn_sched_barrier(0); \
    __builtin_amdgcn_s_setprio(1); \
    MM(IH, JH); \
    __builtin_amdgcn_s_setprio(0); \
    __builtin_amdgcn_sched_barrier(0); \
    __builtin_amdgcn_s_barrier(); \
    __builtin_amdgcn_sched_barrier(0); \
  } while (0)

  // prologue: tile 0 complete + tile 1's B0,A0 (stays in flight, matching
  // the steady-state "leftover from wait(t-1)" invariant)
  if (NK > 1) {
    SA(0, 0, cA0); SA(0, 0, cA1); SB(0, 0, cB0); SB(0, 0, cB1);
    SB(1, 1, cB0); SA(1, 1, cA0);
    asm volatile("s_waitcnt vmcnt(4)" ::: "memory");
  } else {
    SA(0, 0, cA0); SA(0, 0, cA1); SB(0, 0, cB0); SB(0, 0, cB1);
    asm volatile("s_waitcnt vmcnt(0)" ::: "memory");
  }
  __builtin_amdgcn_sched_barrier(0);
  __builtin_amdgcn_s_barrier();
  __builtin_amdgcn_sched_barrier(0);

  for (int t = 0; t < NK; ++t) {
    const int p = t & 1, po = p ^ 1;
    const bool s1 = (t + 1 < NK), s2 = (t + 2 < NK);
    PH(0, 0, LDA(p, 0); LDB(p, 0); if (s1) SA(po, t + 1, cA1); );
    PH(1, 0, LDA(p, 1);            if (s1) SB(po, t + 1, cB1); );
    PH(0, 1, LDA(p, 0); LDB(p, 1); if (s2) SB(p, t + 2, cB0); );
    PH(1, 1, LDA(p, 1);
             if (s2) SA(p, t + 2, cA0);
             if (s2)      { asm volatile("s_waitcnt vmcnt(4)" ::: "memory"); }
             else if (s1) { asm volatile("s_waitcnt vmcnt(0)" ::: "memory"); } );
  }
#undef PH
}

// per-element epilogue: body(rr, cc, av) within the 256x256 tile
template<typename F>
__device__ __forceinline__ void epi8(const f32x4 (&acc)[8][4], F body) {
  const int lane = threadIdx.x & 63;
  const int wave = threadIdx.x >> 6;
  const int mwr = (wave >> 2) * 128, nwr = (wave & 3) * 64;
#pragma unroll
  for (int i = 0; i < 8; ++i)
#pragma unroll
    for (int j = 0; j < 4; ++j)
#pragma unroll
      for (int jj = 0; jj < 4; ++jj)
        body(mwr + i * 16 + ((lane >> 4) << 2) + jj,
             nwr + j * 16 + (lane & 15), acc[i][j][jj]);
}

// ---------------- prep kernels ----------------

__global__ void k_prep_x(const float* __restrict__ x, const float* __restrict__ wlr,
                         const float* __restrict__ wwd, unsigned short* __restrict__ xb,
                         float* __restrict__ lrlog, float* __restrict__ wdlog) {
  const int wave = threadIdx.x >> 6, lane = threadIdx.x & 63;
  const int row = blockIdx.x * 4 + wave;
  const float* xr = x + (size_t)row * DD;
  float s1 = 0.f, s2 = 0.f;
#pragma unroll
  for (int ch = 0; ch < 4; ++ch) {
    const int col = ch * 256 + lane * 4;
    float4 v = *(const float4*)(xr + col);
    float4 a = *(const float4*)(wlr + col);
    float4 b = *(const float4*)(wwd + col);
    s1 += v.x*a.x + v.y*a.y + v.z*a.z + v.w*a.w;
    s2 += v.x*b.x + v.y*b.y + v.z*b.z + v.w*b.w;
    uint2 u;
    u.x = (unsigned)f2bf(v.x) | ((unsigned)f2bf(v.y) << 16);
    u.y = (unsigned)f2bf(v.z) | ((unsigned)f2bf(v.w) << 16);
    *(uint2*)(xb + (size_t)row * DD + col) = u;
  }
#pragma unroll
  for (int off = 32; off > 0; off >>= 1) {
    s1 += __shfl_down(s1, off);
    s2 += __shfl_down(s2, off);
  }
  if (lane == 0) { lrlog[row] = s1; wdlog[row] = s2; }
}

__global__ void k_prep_w(const float* __restrict__ wq, const float* __restrict__ wk,
                         const float* __restrict__ wv, unsigned short* __restrict__ wqt,
                         unsigned short* __restrict__ wkt, unsigned short* __restrict__ wvtn,
                         unsigned short* __restrict__ wkr) {
  const int idx = blockIdx.x * 256 + threadIdx.x;
  if (blockIdx.z == 3) { wkr[idx] = f2bf(wk[idx]); return; }
  const int k = idx >> 10, n = idx & 1023;
  const float* src = (blockIdx.z == 0) ? wq : (blockIdx.z == 1) ? wk : wv;
  unsigned short* dst = (blockIdx.z == 0) ? wqt : (blockIdx.z == 1) ? wkt : wvtn;
  float v = src[(size_t)k * 1024 + n];
  if (blockIdx.z == 2) v = -v;
  dst[(size_t)n * 1024 + k] = f2bf(v);
}

__global__ void k_prep_h(const float* __restrict__ hid, unsigned short* __restrict__ wpb) {
  const size_t i = ((size_t)blockIdx.x * 256 + threadIdx.x) * 4;
  float4 v = *(const float4*)(hid + i);
  uint2 u;
  u.x = (unsigned)f2bf(v.x) | ((unsigned)f2bf(v.y) << 16);
  u.y = (unsigned)f2bf(v.z) | ((unsigned)f2bf(v.w) << 16);
  *(uint2*)(wpb + i) = u;
}

__global__ void k_bias2(const unsigned short* __restrict__ wpb, const float* __restrict__ bk,
                        const float* __restrict__ bv, float* __restrict__ bias2) {
  const int wave = threadIdx.x >> 6, lane = threadIdx.x & 63;
  const int row = blockIdx.x * 4 + wave;
  const unsigned short* wr = wpb + (size_t)row * HH;
  float s = 0.f;
#pragma unroll
  for (int ch = 0; ch < 4; ++ch) {
    const int col = ch * 256 + lane * 4;
    float4 a = *(const float4*)(bk + col);
    ushort4 u = *(const ushort4*)(wr + col);
    s += a.x * bf2f(u.x) + a.y * bf2f(u.y) + a.z * bf2f(u.z) + a.w * bf2f(u.w);
  }
#pragma unroll
  for (int off = 32; off > 0; off >>= 1) s += __shfl_down(s, off);
  if (lane == 0) bias2[row] = s - bv[row & 1023];
}

__global__ void k_scan(const float* __restrict__ lrlog, const float* __restrict__ wdlog,
                       const float* __restrict__ lbl, const float* __restrict__ blr,
                       const float* __restrict__ lbw, const float* __restrict__ bwd,
                       float* __restrict__ lr, float* __restrict__ c,
                       float* __restrict__ s, float* __restrict__ ecl) {
  const int b = blockIdx.x, t = threadIdx.x;
  __shared__ float sums[256];
  const float elr = expf(lbl[0]);
  const float ewd = expf(lbw[0]);
  const float blr0 = blr[0], bwd0 = bwd[0];
  float lw[8];
  const float* wb = wdlog + (size_t)b * LL + t * 8;
  float tot = 0.f;
#pragma unroll
  for (int i = 0; i < 8; ++i) {
    float z = wb[i] + bwd0;
    float sig = 1.f / (1.f + expf(-z));
    tot += log1pf(-ewd * sig);
    lw[i] = tot;
  }
  sums[t] = tot;
  __syncthreads();
  for (int off = 1; off < 256; off <<= 1) {
    float v = (t >= off) ? sums[t - off] : 0.f;
    __syncthreads();
    sums[t] += v;
    __syncthreads();
  }
  const float prev = (t > 0) ? sums[t - 1] : 0.f;
  const float ctot = sums[255];
  const float* lb = lrlog + (size_t)b * LL + t * 8;
#pragma unroll
  for (int i = 0; i < 8; ++i) {
    const int idx = b * LL + t * 8 + i;
    const float ci = prev + lw[i];
    c[idx] = ci;
    float zl = lb[i] + blr0;
    float lri = elr / (1.f + expf(-zl));
    lr[idx] = lri;
    s[idx] = lri * expf(ctot - ci);
  }
  if (t == 0) ecl[b] = expf(ctot);
}

// ---------------- GEMM kernels ----------------

// W2T[b][d][j] = sum_h Wp[b,d,h]*Wk[j,h] - Wv[j,d]
__global__ __launch_bounds__(512, 2) void k8_gemm_m2(const unsigned short* __restrict__ wpb,
    const unsigned short* __restrict__ wkr, const unsigned short* __restrict__ wvtn,
    unsigned short* __restrict__ w2t) {
  __shared__ Smem8 sm;
  const int b = blockIdx.x;
  const int mt = blockIdx.y & 3, nt = blockIdx.y >> 2;
  const int m0 = mt * 256, n0 = nt * 256;
  f32x4 acc[8][4]; acc_init8(acc);
  gemm8_core(
    [&](int r, int kt) { return wpb + (size_t)b * DD * HH + (size_t)(m0 + r) * HH + kt * 64; },
    [&](int r, int kt) { return wkr + (size_t)(n0 + r) * HH + kt * 64; },
    HH / 64, &sm, acc);
  epi8(acc, [&](int rr, int cc, float av) {
    const size_t gi = (size_t)(m0 + rr) * DD + (n0 + cc);
    w2t[(size_t)b * DD * DD + gi] = f2bf(av + bf2f(wvtn[gi]));   // wvtn = -Wv^T
  });
}

// Q = X*WqT + bq; q2 = exp(c[m]) * Q
__global__ __launch_bounds__(512, 2) void k8_gemm_q(const unsigned short* __restrict__ xb,
    const unsigned short* __restrict__ wt, const float* __restrict__ bias,
    const float* __restrict__ c, unsigned short* __restrict__ outb,
    unsigned short* __restrict__ q2b) {
  __shared__ Smem8 sm;
  const int mt = blockIdx.x * 8 + (blockIdx.y & 7);  // XCD x owns 8 contiguous row-tiles
  const int nt = blockIdx.y >> 3;
  const int m0 = mt * 256, n0 = nt * 256;
  f32x4 acc[8][4]; acc_init8(acc);
  gemm8_core(
    [&](int r, int kt) { return xb + (size_t)(m0 + r) * DD + kt * 64; },
    [&](int r, int kt) { return wt + (size_t)(n0 + r) * DD + kt * 64; },
    DD / 64, &sm, acc);
  const int lane = threadIdx.x & 63, wave = threadIdx.x >> 6;
  const int mwr = (wave >> 2) * 128, nwr = (wave & 3) * 64;
  float er[8][4];
#pragma unroll
  for (int i = 0; i < 8; ++i)
#pragma unroll
    for (int jj = 0; jj < 4; ++jj)
      er[i][jj] = __expf(c[m0 + mwr + i * 16 + ((lane >> 4) << 2) + jj]);
#pragma unroll
  for (int i = 0; i < 8; ++i)
#pragma unroll
    for (int j = 0; j < 4; ++j)
#pragma unroll
      for (int jj = 0; jj < 4; ++jj) {
        const int row = m0 + mwr + i * 16 + ((lane >> 4) << 2) + jj;
        const int col = n0 + nwr + j * 16 + (lane & 15);
        const float v = acc[i][j][jj] + bias[col];
        outb[(size_t)row * HH + col] = f2bf(v);
        q2b[(size_t)row * HH + col] = f2bf(v * er[i][jj]);
      }
}

__global__ __launch_bounds__(512, 2) void k8_gemm_k(const unsigned short* __restrict__ xb,
    const unsigned short* __restrict__ wt, const float* __restrict__ bias,
    const float* __restrict__ s, unsigned short* __restrict__ kb,
    unsigned short* __restrict__ k2t) {
  __shared__ Smem8 sm;
  const int mt = blockIdx.x * 8 + (blockIdx.y & 7);
  const int nt = blockIdx.y >> 3;
  const int m0 = mt * 256, n0 = nt * 256;
  f32x4 acc[8][4]; acc_init8(acc);
  gemm8_core(
    [&](int r, int kt) { return xb + (size_t)(m0 + r) * DD + kt * 64; },
    [&](int r, int kt) { return wt + (size_t)(n0 + r) * DD + kt * 64; },
    DD / 64, &sm, acc);
  const int lane = threadIdx.x & 63, wave = threadIdx.x >> 6;
  const int mwr = (wave >> 2) * 128, nwr = (wave & 3) * 64;
#pragma unroll
  for (int i = 0; i < 8; ++i)
#pragma unroll
    for (int j = 0; j < 4; ++j) {
      const int col = n0 + nwr + j * 16 + (lane & 15);
      const float bias_c = bias[col];
      const int row0 = m0 + mwr + i * 16 + ((lane >> 4) << 2);
      const int b = row0 >> 11, ml0 = row0 & 2047;
      unsigned short tmp[4];
#pragma unroll
      for (int jj = 0; jj < 4; ++jj) {
        float v = acc[i][j][jj] + bias_c;
        kb[(size_t)(row0 + jj) * HH + col] = f2bf(v);
        tmp[jj] = f2bf(v * s[row0 + jj]);
      }
      uint2 u;
      u.x = (unsigned)tmp[0] | ((unsigned)tmp[1] << 16);
      u.y = (unsigned)tmp[2] | ((unsigned)tmp[3] << 16);
      *(uint2*)&k2t[((size_t)b * HH + col) * LL + ml0] = u;
    }
}

// U = X*W2T + bias2, stored transposed ut[b][d][l]
__global__ __launch_bounds__(512, 2) void k8_gemm_u(const unsigned short* __restrict__ xb,
    const unsigned short* __restrict__ w2t, const float* __restrict__ bias2,
    unsigned short* __restrict__ ut) {
  __shared__ Smem8 sm;
  const int b = blockIdx.x;
  const int mt = blockIdx.x * 8 + (blockIdx.y & 7);
  const int nt = blockIdx.y >> 3;
  const int m0 = mt * 256, n0 = nt * 256;
  f32x4 acc[8][4]; acc_init8(acc);
  gemm8_core(
    [&](int r, int kt) { return xb + (size_t)(m0 + r) * DD + kt * 64; },
    [&](int r, int kt) { return w2t + (size_t)b * DD * DD + (size_t)(n0 + r) * DD + kt * 64; },
    DD / 64, &sm, acc);
  const int lane = threadIdx.x & 63, wave = threadIdx.x >> 6;
  const int mwr = (wave >> 2) * 128, nwr = (wave & 3) * 64;
#pragma unroll
  for (int i = 0; i < 8; ++i)
#pragma unroll
    for (int j = 0; j < 4; ++j) {
      const int col = n0 + nwr + j * 16 + (lane & 15);
      const float b2c = bias2[b * DD + col];
      const int row0 = m0 + mwr + i * 16 + ((lane >> 4) << 2);
      const int ml0 = row0 & 2047;
      unsigned short tmp[4];
#pragma unroll
      for (int jj = 0; jj < 4; ++jj) tmp[jj] = f2bf(acc[i][j][jj] + b2c);
      uint2 u;
      u.x = (unsigned)tmp[0] | ((unsigned)tmp[1] << 16);
      u.y = (unsigned)tmp[2] | ((unsigned)tmp[3] << 16);
      *(uint2*)&ut[((size_t)b * DD + col) * LL + ml0] = u;
    }
}

// pb[m,l] = -lr[l]*exp(c[m]-c[l]) * (Q K^T)[m,l] for l<=m, else 0.
// 256x256 triangular tiles: per batch 36 tiles (mt 0..7, nt<=mt).
// Off-diagonal: factored decay (both exp args <= 0, c monotone decreasing).
// Diagonal: direct form with mask. Coverage == y's read range exactly.
__global__ __launch_bounds__(512, 2) void k8_gemm_p(const unsigned short* __restrict__ qb,
    const unsigned short* __restrict__ kb, const float* __restrict__ lr,
    const float* __restrict__ c, unsigned short* __restrict__ pb) {
  __shared__ Smem8 sm;
  const int b = blockIdx.x;                    // XCD = batch (L2 locality)
  const int t = blockIdx.y;                    // 0..35
  int mt = (int)((sqrtf(8.f * (float)t + 1.f) - 1.f) * 0.5f);
  while ((mt + 1) * (mt + 2) / 2 <= t) ++mt;
  while (mt * (mt + 1) / 2 > t) --mt;
  const int nt = t - mt * (mt + 1) / 2;
  const int base = b * LL;
  const int m0 = mt * 256, n0 = nt * 256;
  f32x4 acc[8][4]; acc_init8(acc);
  gemm8_core(
    [&](int rr, int kt) { return qb + (size_t)(base + m0 + rr) * HH + kt * 64; },
    [&](int rr, int kt) { return kb + (size_t)(base + n0 + rr) * HH + kt * 64; },
    HH / 64, &sm, acc);
  const int lane = threadIdx.x & 63, wave = threadIdx.x >> 6;
  const int mwr = (wave >> 2) * 128, nwr = (wave & 3) * 64;
  if (nt != mt) {
    const float cref = c[base + m0];
    float er[8][4], fc[4];
#pragma unroll
    for (int i = 0; i < 8; ++i)
#pragma unroll
      for (int jj = 0; jj < 4; ++jj)
        er[i][jj] = __expf(c[base + m0 + mwr + i * 16 + ((lane >> 4) << 2) + jj] - cref);
#pragma unroll
    for (int j = 0; j < 4; ++j) {
      const int l = n0 + nwr + j * 16 + (lane & 15);
      fc[j] = lr[base + l] * __expf(cref - c[base + l]);
    }
#pragma unroll
    for (int i = 0; i < 8; ++i)
#pragma unroll
      for (int j = 0; j < 4; ++j) {
        const int l = n0 + nwr + j * 16 + (lane & 15);
        const int row0 = m0 + mwr + i * 16 + ((lane >> 4) << 2);
#pragma unroll
        for (int jj = 0; jj < 4; ++jj) {
          const float v = -acc[i][j][jj] * er[i][jj] * fc[j];
          pb[((size_t)base + row0 + jj) * LL + l] = f2bf(v);
        }
      }
  } else {
    epi8(acc, [&](int rr, int cc, float av) {
      const int m = m0 + rr, l = n0 + cc;
      float v = 0.f;
      if (l <= m) v = -av * lr[base + l] * __expf(c[base + m] - c[base + l]);
      pb[((size_t)base + m) * LL + l] = f2bf(v);
    });
  }
}

// y = pb*U + q2*Wp^T, fused into one pipelined K-sequence.
// Grid (8,32): x = batch (XCD), mt = y&7, nt = y>>3; all 32 blocks/XCD co-resident.
__global__ __launch_bounds__(512, 2) void k8_gemm_y(const unsigned short* __restrict__ pb,
    const unsigned short* __restrict__ ut, const unsigned short* __restrict__ q2b,
    const unsigned short* __restrict__ wpb, float* __restrict__ out) {
  __shared__ Smem8 sm;
  const int b = blockIdx.x;
  const int mt = blockIdx.y & 7;
  const int nt = blockIdx.y >> 3;
  const int m0 = mt * 256, n0 = nt * 256;
  const int NK1 = (mt + 1) * 4;                 // pb cols l < (mt+1)*256
  f32x4 acc[8][4]; acc_init8(acc);
  gemm8_core(
    [&](int r, int kt) {
      return (kt < NK1) ? pb + (size_t)b * LL * LL + (size_t)(m0 + r) * LL + kt * 64
                        : q2b + ((size_t)b * LL + m0 + r) * HH + (kt - NK1) * 64;
    },
    [&](int r, int kt) {
      return (kt < NK1) ? ut + (size_t)b * DD * LL + (size_t)(n0 + r) * LL + kt * 64
                        : wpb + (size_t)b * DD * HH + (size_t)(n0 + r) * HH + (kt - NK1) * 64;
    },
    NK1 + 16, &sm, acc);
  epi8(acc, [&](int rr, int cc, float av) {
    out[((size_t)b * LL + m0 + rr) * DD + (n0 + cc)] = av;
  });
}

// W_next = -Ut * K2t^T + ecl[b]*W_prev
__global__ __launch_bounds__(512, 2) void k8_gemm_wn(const unsigned short* __restrict__ ut,
    const unsigned short* __restrict__ k2t, const float* __restrict__ hid,
    const float* __restrict__ ecl, float* __restrict__ out2) {
  __shared__ Smem8 sm;
  const int b = blockIdx.x;
  const int mt = blockIdx.y & 3, nt = blockIdx.y >> 2;
  const int m0 = mt * 256, n0 = nt * 256;
  f32x4 acc[8][4]; acc_init8(acc);
  gemm8_core(
    [&](int r, int kt) { return ut + (size_t)b * DD * LL + (size_t)(m0 + r) * LL + kt * 64; },
    [&](int r, int kt) { return k2t + (size_t)b * HH * LL + (size_t)(n0 + r) * LL + kt * 64; },
    LL / 64, &sm, acc);
  const float eclb = ecl[b];
  epi8(acc, [&](int rr, int cc, float av) {
    const size_t gi = ((size_t)b * DD + (m0 + rr)) * HH + (n0 + cc);
    out2[gi] = -av + eclb * hid[gi];
  });
}

// ---------------- launcher ----------------

extern "C" void kernel_launch(void* const* d_in, const int* in_sizes, int n_in,
                              void* d_out, int out_size, void* d_ws, size_t ws_size,
                              hipStream_t stream) {
  (void)in_sizes; (void)n_in; (void)out_size; (void)ws_size;
  const float* x   = (const float*)d_in[0];
  const float* hid = (const float*)d_in[1];
  const float* lbl = (const float*)d_in[2];
  const float* wlr = (const float*)d_in[3];
  const float* blr = (const float*)d_in[4];
  const float* lbw = (const float*)d_in[5];
  const float* wwd = (const float*)d_in[6];
  const float* bwd = (const float*)d_in[7];
  const float* wq  = (const float*)d_in[8];
  const float* bq  = (const float*)d_in[9];
  const float* wk  = (const float*)d_in[10];
  const float* bk  = (const float*)d_in[11];
  const float* wv  = (const float*)d_in[12];
  const float* bv  = (const float*)d_in[13];
  float* out = (float*)d_out;

  char* w = (char*)d_ws;
  constexpr size_t SZ_XB  = (size_t)BL * DD * 2;
  constexpr size_t SZ_QB  = (size_t)BL * HH * 2;
  constexpr size_t SZ_KB  = (size_t)BL * HH * 2;
  constexpr size_t SZ_K2T = (size_t)BB * HH * LL * 2;
  constexpr size_t SZ_UT  = (size_t)BB * DD * LL * 2;
  constexpr size_t SZ_PB  = (size_t)BB * LL * LL * 2;
  constexpr size_t SZ_WT  = (size_t)DD * HH * 2;
  constexpr size_t SZ_WPB = (size_t)BB * DD * HH * 2;
  constexpr size_t SZ_V16 = (size_t)BL * 4;

  size_t off = 0;
  unsigned short* xb   = (unsigned short*)(w + off); off += SZ_XB;
  unsigned short* qb   = (unsigned short*)(w + off); off += SZ_QB;
  unsigned short* kb   = (unsigned short*)(w + off); off += SZ_KB;
  unsigned short* k2t  = (unsigned short*)(w + off); off += SZ_K2T;
  unsigned short* ut   = (unsigned short*)(w + off); off += SZ_UT;
  unsigned short* pb   = (unsigned short*)(w + off); off += SZ_PB;
  unsigned short* wqt  = (unsigned short*)(w + off); off += SZ_WT;
  unsigned short* wkt  = (unsigned short*)(w + off); off += SZ_WT;
  unsigned short* wvtn = (unsigned short*)(w + off); off += SZ_WT;
  unsigned short* wpb  = (unsigned short*)(w + off); off += SZ_WPB;
  float* lrlog = (float*)(w + off); off += SZ_V16;
  float* wdlog = (float*)(w + off); off += SZ_V16;
  float* lr    = (float*)(w + off); off += SZ_V16;
  float* c     = (float*)(w + off); off += SZ_V16;
  float* s     = (float*)(w + off); off += SZ_V16;
  float* ecl   = (float*)(w + off); off += 256;
  float* bias2 = (float*)(w + off); off += (size_t)BB * DD * 4;

  // w2t (16.8 MB) + wkr (2 MB) alias the pb region: dead before k8_gemm_p writes pb.
  unsigned short* w2t = pb;
  unsigned short* wkr = pb + (size_t)BB * DD * DD;

  // q2 scratch lives in d_out's W_next region; overwritten by k8_gemm_wn afterwards.
  unsigned short* q2b = (unsigned short*)(out + (size_t)BL * DD);
  float* out2 = out + (size_t)BL * DD;

  k_prep_x<<<dim3(BL / 4), 256, 0, stream>>>(x, wlr, wwd, xb, lrlog, wdlog);
  k_prep_w<<<dim3(4096, 1, 4), 256, 0, stream>>>(wq, wk, wv, wqt, wkt, wvtn, wkr);
  k_prep_h<<<dim3((unsigned)((size_t)BB * DD * HH / 1024)), 256, 0, stream>>>(hid, wpb);
  k_scan<<<dim3(BB), 256, 0, stream>>>(lrlog, wdlog, lbl, blr, lbw, bwd, lr, c, s, ecl);
  k_bias2<<<dim3(BB * DD / 4), 256, 0, stream>>>(wpb, bk, bv, bias2);

  k8_gemm_m2<<<dim3(8, 16), 512, 0, stream>>>(wpb, wkr, wvtn, w2t);
  k8_gemm_q<<<dim3(8, 32), 512, 0, stream>>>(xb, wqt, bq, c, qb, q2b);
  k8_gemm_k<<<dim3(8, 32), 512, 0, stream>>>(xb, wkt, bk, s, kb, k2t);
  k8_gemm_u<<<dim3(8, 32), 512, 0, stream>>>(xb, w2t, bias2, ut);
  k8_gemm_p<<<dim3(8, 36), 512, 0, stream>>>(qb, kb, lr, c, pb);
  k8_gemm_y<<<dim3(8, 32), 512, 0, stream>>>(pb, ut, q2b, wpb, out);
  k8_gemm_wn<<<dim3(8, 16), 512, 0, stream>>>(ut, k2t, hid, ecl, out2);
}

// Round 5
// 610.139 us; speedup vs baseline: 1.0643x; 1.0643x over previous
//
#include <hip/hip_runtime.h>
#include <stdint.h>

#define BB 8
#define LL 2048
#define DD 1024
#define HH 1024
#define BL (BB*LL)   // 16384

typedef __attribute__((ext_vector_type(8))) short short8;
typedef __attribute__((ext_vector_type(4))) float f32x4;

__device__ __forceinline__ unsigned short f2bf(float f) {
  unsigned int x = __float_as_uint(f);
  unsigned int r = (x + 0x7fffu + ((x >> 16) & 1u)) >> 16;
  return (unsigned short)r;
}
__device__ __forceinline__ float bf2f(unsigned short u) {
  return __uint_as_float(((unsigned int)u) << 16);
}

__device__ __forceinline__ void stage16(const unsigned short* g, unsigned short* l) {
  __builtin_amdgcn_global_load_lds((const __attribute__((address_space(1))) void*)g,
                                   (__attribute__((address_space(3))) void*)l,
                                   16, 0, 0);
}

// ================= v5 core: minimal-LDS-read 2-phase counted-vmcnt =================
// 512 threads = 8 waves (2M x 4N), BM=BN=256, BK=64. LDS 2 buffers = 128 KiB.
// Per K-tile per wave: 24 ds_read_b128 (minimum: A-panel 16KB + B-panel 8KB),
// 64 MFMA in 4 clusters of 16, TWO s_barriers, one counted vmcnt(4).
//   PH1: [SA(t+1)->po ; LDB(p): bfv[4][2] (8 rd) ; LDA(ih0,kk0): af[4] (4 rd)]
//        lgkm0 ; MM(ih0,kk0)x16 ; LDA(ih0,kk1) ; lgkm0 ; MM(ih0,kk1)x16 ; barrier
//   PH2: [SB(t+2)->p ; LDA(ih1,kk0)] lgkm0 ; MM(ih1,kk0) ; LDA(ih1,kk1) ; lgkm0 ;
//        MM(ih1,kk1) ; vmcnt(4) ; barrier
// Hazards: SB(t+2) overwrites p.b AFTER ph1's trailing barrier (all waves' B-reads
// complete before their first lgkm0); SA(t+1) overwrites po.a whose last reads
// (iter t-1 ph2) completed before that iter's final barrier. vmcnt ledger (per
// wave, gload_lds only): prologue {A0,B0}=8 + {B1}=4 -> vmcnt(4) drains tile 0.
// Steady state at end of iter t: [B(t+1):4][A(t+1):4][B(t+2):4] -> vmcnt(4)
// drains tile t+1 exactly, leaves B(t+2) flying (T4: never 0 mid-loop).
// Tails: t+2==NK -> vmcnt(0) (8 outstanding); t+1==NK -> nothing outstanding.
struct __align__(16) Smem8 {
  unsigned short a[2][16384];   // 256 x 64 per buffer
  unsigned short b[2][16384];
};
static_assert(sizeof(Smem8) == 131072, "LDS size");

__device__ __forceinline__ void acc_init8(f32x4 (&acc)[8][4]) {
#pragma unroll
  for (int i = 0; i < 8; ++i)
#pragma unroll
    for (int j = 0; j < 4; ++j)
      acc[i][j] = (f32x4){0.f, 0.f, 0.f, 0.f};
}

template<class FA, class FB>
__device__ __forceinline__ void gemm8_core(FA srcA, FB srcB, int NK,
                                           Smem8* sm, f32x4 (&acc)[8][4]) {
  const int lane = threadIdx.x & 63;
  const int wave = threadIdx.x >> 6;           // 0..7
  const int srow = lane >> 3;                  // 0..7
  const int scol = ((lane & 7) ^ srow) * 8;    // swizzled source column
  const int fk = (lane >> 4) * 8;
  const int fr = lane & 15;
  const int fx = fr & 7;
  const int mwr = (wave >> 2) * 128;           // wave row base
  const int nwr = (wave & 3) * 64;             // wave col base
  // per-wave stage chunk bases (2 consecutive chunks per call)
  const int cA0 = (wave < 4) ? 2 * wave : 2 * wave + 8;   // {0-7,16-23}
  const int cA1 = cA0 + 8;                                 // {8-15,24-31}
  const int cB0 = (wave >> 1) * 8 + 2 * (wave & 1);        // {c:(c&7)<4}
  const int cB1 = cB0 + 4;                                 // {c:(c&7)>=4}

  auto SA = [&](int p, int kt, int c) {
    stage16(srcA(c * 8 + srow, kt) + scol, &sm->a[p][c * 512]);
    stage16(srcA(c * 8 + 8 + srow, kt) + scol, &sm->a[p][(c + 1) * 512]);
  };
  auto SB = [&](int p, int kt, int c) {
    stage16(srcB(c * 8 + srow, kt) + scol, &sm->b[p][c * 512]);
    stage16(srcB(c * 8 + 8 + srow, kt) + scol, &sm->b[p][(c + 1) * 512]);
  };
  const int kc0 = (((fk >> 3) ^ fx) << 3);            // byte col for kk=0
  const int kc1 = ((((32 + fk) >> 3) ^ fx) << 3);     // byte col for kk=1

  short8 af[4], bfv[4][2];
  auto LDB = [&](int p) {
#pragma unroll
    for (int j = 0; j < 4; ++j) {
      bfv[j][0] = *(const short8*)&sm->b[p][(nwr + j * 16 + fr) * 64 + kc0];
      bfv[j][1] = *(const short8*)&sm->b[p][(nwr + j * 16 + fr) * 64 + kc1];
    }
  };
  auto LDA4 = [&](int p, int ih, int kc) {
#pragma unroll
    for (int i = 0; i < 4; ++i)
      af[i] = *(const short8*)&sm->a[p][(mwr + ih * 64 + i * 16 + fr) * 64 + kc];
  };
  auto MMk = [&](int ih, int kk) {
#pragma unroll
    for (int i = 0; i < 4; ++i)
#pragma unroll
      for (int j = 0; j < 4; ++j)
        acc[ih * 4 + i][j] = __builtin_amdgcn_mfma_f32_16x16x32_bf16(
            af[i], bfv[j][kk], acc[ih * 4 + i][j], 0, 0, 0);
  };

#define LGKM0 do { asm volatile("s_waitcnt lgkmcnt(0)" ::: "memory"); \
                   __builtin_amdgcn_sched_barrier(0); } while (0)

  // prologue: tile 0 (A+B -> buf0) + B(1) -> buf1
  SA(0, 0, cA0); SA(0, 0, cA1); SB(0, 0, cB0); SB(0, 0, cB1);
  if (NK > 1) {
    SB(1, 1, cB0); SB(1, 1, cB1);
    asm volatile("s_waitcnt vmcnt(4)" ::: "memory");
  } else {
    asm volatile("s_waitcnt vmcnt(0)" ::: "memory");
  }
  __builtin_amdgcn_sched_barrier(0);
  __builtin_amdgcn_s_barrier();
  __builtin_amdgcn_sched_barrier(0);

  for (int t = 0; t < NK; ++t) {
    const int p = t & 1, po = p ^ 1;
    const bool s1 = (t + 1 < NK), s2 = (t + 2 < NK);
    // ---- PH1: ih = 0 ----
    if (s1) { SA(po, t + 1, cA0); SA(po, t + 1, cA1); }
    LDB(p);
    LDA4(p, 0, kc0);
    LGKM0;
    __builtin_amdgcn_s_setprio(1); MMk(0, 0); __builtin_amdgcn_s_setprio(0);
    LDA4(p, 0, kc1);
    LGKM0;
    __builtin_amdgcn_s_setprio(1); MMk(0, 1); __builtin_amdgcn_s_setprio(0);
    __builtin_amdgcn_sched_barrier(0);
    __builtin_amdgcn_s_barrier();
    __builtin_amdgcn_sched_barrier(0);
    // ---- PH2: ih = 1 ----
    if (s2) { SB(p, t + 2, cB0); SB(p, t + 2, cB1); }
    LDA4(p, 1, kc0);
    LGKM0;
    __builtin_amdgcn_s_setprio(1); MMk(1, 0); __builtin_amdgcn_s_setprio(0);
    LDA4(p, 1, kc1);
    LGKM0;
    __builtin_amdgcn_s_setprio(1); MMk(1, 1); __builtin_amdgcn_s_setprio(0);
    __builtin_amdgcn_sched_barrier(0);
    if (s2)      { asm volatile("s_waitcnt vmcnt(4)" ::: "memory"); }
    else if (s1) { asm volatile("s_waitcnt vmcnt(0)" ::: "memory"); }
    __builtin_amdgcn_sched_barrier(0);
    __builtin_amdgcn_s_barrier();
    __builtin_amdgcn_sched_barrier(0);
  }
#undef LGKM0
}

// per-element epilogue: body(rr, cc, av) within the 256x256 tile
template<typename F>
__device__ __forceinline__ void epi8(const f32x4 (&acc)[8][4], F body) {
  const int lane = threadIdx.x & 63;
  const int wave = threadIdx.x >> 6;
  const int mwr = (wave >> 2) * 128, nwr = (wave & 3) * 64;
#pragma unroll
  for (int i = 0; i < 8; ++i)
#pragma unroll
    for (int j = 0; j < 4; ++j)
#pragma unroll
      for (int jj = 0; jj < 4; ++jj)
        body(mwr + i * 16 + ((lane >> 4) << 2) + jj,
             nwr + j * 16 + (lane & 15), acc[i][j][jj]);
}

// ---------------- prep kernels ----------------

__global__ void k_prep_x(const float* __restrict__ x, const float* __restrict__ wlr,
                         const float* __restrict__ wwd, unsigned short* __restrict__ xb,
                         float* __restrict__ lrlog, float* __restrict__ wdlog) {
  const int wave = threadIdx.x >> 6, lane = threadIdx.x & 63;
  const int row = blockIdx.x * 4 + wave;
  const float* xr = x + (size_t)row * DD;
  float s1 = 0.f, s2 = 0.f;
#pragma unroll
  for (int ch = 0; ch < 4; ++ch) {
    const int col = ch * 256 + lane * 4;
    float4 v = *(const float4*)(xr + col);
    float4 a = *(const float4*)(wlr + col);
    float4 b = *(const float4*)(wwd + col);
    s1 += v.x*a.x + v.y*a.y + v.z*a.z + v.w*a.w;
    s2 += v.x*b.x + v.y*b.y + v.z*b.z + v.w*b.w;
    uint2 u;
    u.x = (unsigned)f2bf(v.x) | ((unsigned)f2bf(v.y) << 16);
    u.y = (unsigned)f2bf(v.z) | ((unsigned)f2bf(v.w) << 16);
    *(uint2*)(xb + (size_t)row * DD + col) = u;
  }
#pragma unroll
  for (int off = 32; off > 0; off >>= 1) {
    s1 += __shfl_down(s1, off);
    s2 += __shfl_down(s2, off);
  }
  if (lane == 0) { lrlog[row] = s1; wdlog[row] = s2; }
}

__global__ void k_prep_w(const float* __restrict__ wq, const float* __restrict__ wk,
                         const float* __restrict__ wv, unsigned short* __restrict__ wqt,
                         unsigned short* __restrict__ wkt, unsigned short* __restrict__ wvtn,
                         unsigned short* __restrict__ wkr) {
  const int idx = blockIdx.x * 256 + threadIdx.x;
  if (blockIdx.z == 3) { wkr[idx] = f2bf(wk[idx]); return; }
  const int k = idx >> 10, n = idx & 1023;
  const float* src = (blockIdx.z == 0) ? wq : (blockIdx.z == 1) ? wk : wv;
  unsigned short* dst = (blockIdx.z == 0) ? wqt : (blockIdx.z == 1) ? wkt : wvtn;
  float v = src[(size_t)k * 1024 + n];
  if (blockIdx.z == 2) v = -v;
  dst[(size_t)n * 1024 + k] = f2bf(v);
}

__global__ void k_prep_h(const float* __restrict__ hid, unsigned short* __restrict__ wpb) {
  const size_t i = ((size_t)blockIdx.x * 256 + threadIdx.x) * 4;
  float4 v = *(const float4*)(hid + i);
  uint2 u;
  u.x = (unsigned)f2bf(v.x) | ((unsigned)f2bf(v.y) << 16);
  u.y = (unsigned)f2bf(v.z) | ((unsigned)f2bf(v.w) << 16);
  *(uint2*)(wpb + i) = u;
}

__global__ void k_bias2(const unsigned short* __restrict__ wpb, const float* __restrict__ bk,
                        const float* __restrict__ bv, float* __restrict__ bias2) {
  const int wave = threadIdx.x >> 6, lane = threadIdx.x & 63;
  const int row = blockIdx.x * 4 + wave;
  const unsigned short* wr = wpb + (size_t)row * HH;
  float s = 0.f;
#pragma unroll
  for (int ch = 0; ch < 4; ++ch) {
    const int col = ch * 256 + lane * 4;
    float4 a = *(const float4*)(bk + col);
    ushort4 u = *(const ushort4*)(wr + col);
    s += a.x * bf2f(u.x) + a.y * bf2f(u.y) + a.z * bf2f(u.z) + a.w * bf2f(u.w);
  }
#pragma unroll
  for (int off = 32; off > 0; off >>= 1) s += __shfl_down(s, off);
  if (lane == 0) bias2[row] = s - bv[row & 1023];
}

__global__ void k_scan(const float* __restrict__ lrlog, const float* __restrict__ wdlog,
                       const float* __restrict__ lbl, const float* __restrict__ blr,
                       const float* __restrict__ lbw, const float* __restrict__ bwd,
                       float* __restrict__ lr, float* __restrict__ c,
                       float* __restrict__ s, float* __restrict__ ecl) {
  const int b = blockIdx.x, t = threadIdx.x;
  __shared__ float sums[256];
  const float elr = expf(lbl[0]);
  const float ewd = expf(lbw[0]);
  const float blr0 = blr[0], bwd0 = bwd[0];
  float lw[8];
  const float* wb = wdlog + (size_t)b * LL + t * 8;
  float tot = 0.f;
#pragma unroll
  for (int i = 0; i < 8; ++i) {
    float z = wb[i] + bwd0;
    float sig = 1.f / (1.f + expf(-z));
    tot += log1pf(-ewd * sig);
    lw[i] = tot;
  }
  sums[t] = tot;
  __syncthreads();
  for (int off = 1; off < 256; off <<= 1) {
    float v = (t >= off) ? sums[t - off] : 0.f;
    __syncthreads();
    sums[t] += v;
    __syncthreads();
  }
  const float prev = (t > 0) ? sums[t - 1] : 0.f;
  const float ctot = sums[255];
  const float* lb = lrlog + (size_t)b * LL + t * 8;
#pragma unroll
  for (int i = 0; i < 8; ++i) {
    const int idx = b * LL + t * 8 + i;
    const float ci = prev + lw[i];
    c[idx] = ci;
    float zl = lb[i] + blr0;
    float lri = elr / (1.f + expf(-zl));
    lr[idx] = lri;
    s[idx] = lri * expf(ctot - ci);
  }
  if (t == 0) ecl[b] = expf(ctot);
}

// ---------------- GEMM kernels ----------------

// W2T[b][d][j] = sum_h Wp[b,d,h]*Wk[j,h] - Wv[j,d]
__global__ __launch_bounds__(512, 2) void k8_gemm_m2(const unsigned short* __restrict__ wpb,
    const unsigned short* __restrict__ wkr, const unsigned short* __restrict__ wvtn,
    unsigned short* __restrict__ w2t) {
  __shared__ Smem8 sm;
  const int b = blockIdx.x;
  const int mt = blockIdx.y & 3, nt = blockIdx.y >> 2;
  const int m0 = mt * 256, n0 = nt * 256;
  f32x4 acc[8][4]; acc_init8(acc);
  gemm8_core(
    [&](int r, int kt) { return wpb + (size_t)b * DD * HH + (size_t)(m0 + r) * HH + kt * 64; },
    [&](int r, int kt) { return wkr + (size_t)(n0 + r) * HH + kt * 64; },
    HH / 64, &sm, acc);
  epi8(acc, [&](int rr, int cc, float av) {
    const size_t gi = (size_t)(m0 + rr) * DD + (n0 + cc);
    w2t[(size_t)b * DD * DD + gi] = f2bf(av + bf2f(wvtn[gi]));   // wvtn = -Wv^T
  });
}

// Q = X*WqT + bq; q2 = exp(c[m]) * Q
__global__ __launch_bounds__(512, 2) void k8_gemm_q(const unsigned short* __restrict__ xb,
    const unsigned short* __restrict__ wt, const float* __restrict__ bias,
    const float* __restrict__ c, unsigned short* __restrict__ outb,
    unsigned short* __restrict__ q2b) {
  __shared__ Smem8 sm;
  const int mt = blockIdx.x * 8 + (blockIdx.y & 7);  // XCD x owns 8 contiguous row-tiles
  const int nt = blockIdx.y >> 3;
  const int m0 = mt * 256, n0 = nt * 256;
  f32x4 acc[8][4]; acc_init8(acc);
  gemm8_core(
    [&](int r, int kt) { return xb + (size_t)(m0 + r) * DD + kt * 64; },
    [&](int r, int kt) { return wt + (size_t)(n0 + r) * DD + kt * 64; },
    DD / 64, &sm, acc);
  const int lane = threadIdx.x & 63, wave = threadIdx.x >> 6;
  const int mwr = (wave >> 2) * 128, nwr = (wave & 3) * 64;
  float er[8][4];
#pragma unroll
  for (int i = 0; i < 8; ++i)
#pragma unroll
    for (int jj = 0; jj < 4; ++jj)
      er[i][jj] = __expf(c[m0 + mwr + i * 16 + ((lane >> 4) << 2) + jj]);
#pragma unroll
  for (int i = 0; i < 8; ++i)
#pragma unroll
    for (int j = 0; j < 4; ++j)
#pragma unroll
      for (int jj = 0; jj < 4; ++jj) {
        const int row = m0 + mwr + i * 16 + ((lane >> 4) << 2) + jj;
        const int col = n0 + nwr + j * 16 + (lane & 15);
        const float v = acc[i][j][jj] + bias[col];
        outb[(size_t)row * HH + col] = f2bf(v);
        q2b[(size_t)row * HH + col] = f2bf(v * er[i][jj]);
      }
}

__global__ __launch_bounds__(512, 2) void k8_gemm_k(const unsigned short* __restrict__ xb,
    const unsigned short* __restrict__ wt, const float* __restrict__ bias,
    const float* __restrict__ s, unsigned short* __restrict__ kb,
    unsigned short* __restrict__ k2t) {
  __shared__ Smem8 sm;
  const int mt = blockIdx.x * 8 + (blockIdx.y & 7);
  const int nt = blockIdx.y >> 3;
  const int m0 = mt * 256, n0 = nt * 256;
  f32x4 acc[8][4]; acc_init8(acc);
  gemm8_core(
    [&](int r, int kt) { return xb + (size_t)(m0 + r) * DD + kt * 64; },
    [&](int r, int kt) { return wt + (size_t)(n0 + r) * DD + kt * 64; },
    DD / 64, &sm, acc);
  const int lane = threadIdx.x & 63, wave = threadIdx.x >> 6;
  const int mwr = (wave >> 2) * 128, nwr = (wave & 3) * 64;
#pragma unroll
  for (int i = 0; i < 8; ++i)
#pragma unroll
    for (int j = 0; j < 4; ++j) {
      const int col = n0 + nwr + j * 16 + (lane & 15);
      const float bias_c = bias[col];
      const int row0 = m0 + mwr + i * 16 + ((lane >> 4) << 2);
      const int b = row0 >> 11, ml0 = row0 & 2047;
      unsigned short tmp[4];
#pragma unroll
      for (int jj = 0; jj < 4; ++jj) {
        float v = acc[i][j][jj] + bias_c;
        kb[(size_t)(row0 + jj) * HH + col] = f2bf(v);
        tmp[jj] = f2bf(v * s[row0 + jj]);
      }
      uint2 u;
      u.x = (unsigned)tmp[0] | ((unsigned)tmp[1] << 16);
      u.y = (unsigned)tmp[2] | ((unsigned)tmp[3] << 16);
      *(uint2*)&k2t[((size_t)b * HH + col) * LL + ml0] = u;
    }
}

// U = X*W2T + bias2, stored transposed ut[b][d][l]
__global__ __launch_bounds__(512, 2) void k8_gemm_u(const unsigned short* __restrict__ xb,
    const unsigned short* __restrict__ w2t, const float* __restrict__ bias2,
    unsigned short* __restrict__ ut) {
  __shared__ Smem8 sm;
  const int b = blockIdx.x;
  const int mt = blockIdx.x * 8 + (blockIdx.y & 7);
  const int nt = blockIdx.y >> 3;
  const int m0 = mt * 256, n0 = nt * 256;
  f32x4 acc[8][4]; acc_init8(acc);
  gemm8_core(
    [&](int r, int kt) { return xb + (size_t)(m0 + r) * DD + kt * 64; },
    [&](int r, int kt) { return w2t + (size_t)b * DD * DD + (size_t)(n0 + r) * DD + kt * 64; },
    DD / 64, &sm, acc);
  const int lane = threadIdx.x & 63, wave = threadIdx.x >> 6;
  const int mwr = (wave >> 2) * 128, nwr = (wave & 3) * 64;
#pragma unroll
  for (int i = 0; i < 8; ++i)
#pragma unroll
    for (int j = 0; j < 4; ++j) {
      const int col = n0 + nwr + j * 16 + (lane & 15);
      const float b2c = bias2[b * DD + col];
      const int row0 = m0 + mwr + i * 16 + ((lane >> 4) << 2);
      const int ml0 = row0 & 2047;
      unsigned short tmp[4];
#pragma unroll
      for (int jj = 0; jj < 4; ++jj) tmp[jj] = f2bf(acc[i][j][jj] + b2c);
      uint2 u;
      u.x = (unsigned)tmp[0] | ((unsigned)tmp[1] << 16);
      u.y = (unsigned)tmp[2] | ((unsigned)tmp[3] << 16);
      *(uint2*)&ut[((size_t)b * DD + col) * LL + ml0] = u;
    }
}

// pb[m,l] = -lr[l]*exp(c[m]-c[l]) * (Q K^T)[m,l] for l<=m, else 0.
// 256x256 triangular tiles: per batch 36 tiles (mt 0..7, nt<=mt).
__global__ __launch_bounds__(512, 2) void k8_gemm_p(const unsigned short* __restrict__ qb,
    const unsigned short* __restrict__ kb, const float* __restrict__ lr,
    const float* __restrict__ c, unsigned short* __restrict__ pb) {
  __shared__ Smem8 sm;
  const int b = blockIdx.x;                    // XCD = batch (L2 locality)
  const int t = blockIdx.y;                    // 0..35
  int mt = (int)((sqrtf(8.f * (float)t + 1.f) - 1.f) * 0.5f);
  while ((mt + 1) * (mt + 2) / 2 <= t) ++mt;
  while (mt * (mt + 1) / 2 > t) --mt;
  const int nt = t - mt * (mt + 1) / 2;
  const int base = b * LL;
  const int m0 = mt * 256, n0 = nt * 256;
  f32x4 acc[8][4]; acc_init8(acc);
  gemm8_core(
    [&](int rr, int kt) { return qb + (size_t)(base + m0 + rr) * HH + kt * 64; },
    [&](int rr, int kt) { return kb + (size_t)(base + n0 + rr) * HH + kt * 64; },
    HH / 64, &sm, acc);
  const int lane = threadIdx.x & 63, wave = threadIdx.x >> 6;
  const int mwr = (wave >> 2) * 128, nwr = (wave & 3) * 64;
  if (nt != mt) {
    const float cref = c[base + m0];
    float er[8][4], fc[4];
#pragma unroll
    for (int i = 0; i < 8; ++i)
#pragma unroll
      for (int jj = 0; jj < 4; ++jj)
        er[i][jj] = __expf(c[base + m0 + mwr + i * 16 + ((lane >> 4) << 2) + jj] - cref);
#pragma unroll
    for (int j = 0; j < 4; ++j) {
      const int l = n0 + nwr + j * 16 + (lane & 15);
      fc[j] = lr[base + l] * __expf(cref - c[base + l]);
    }
#pragma unroll
    for (int i = 0; i < 8; ++i)
#pragma unroll
      for (int j = 0; j < 4; ++j) {
        const int l = n0 + nwr + j * 16 + (lane & 15);
        const int row0 = m0 + mwr + i * 16 + ((lane >> 4) << 2);
#pragma unroll
        for (int jj = 0; jj < 4; ++jj) {
          const float v = -acc[i][j][jj] * er[i][jj] * fc[j];
          pb[((size_t)base + row0 + jj) * LL + l] = f2bf(v);
        }
      }
  } else {
    epi8(acc, [&](int rr, int cc, float av) {
      const int m = m0 + rr, l = n0 + cc;
      float v = 0.f;
      if (l <= m) v = -av * lr[base + l] * __expf(c[base + m] - c[base + l]);
      pb[((size_t)base + m) * LL + l] = f2bf(v);
    });
  }
}

// y = pb*U + q2*Wp^T, fused into one pipelined K-sequence.
// Grid (8,32): x = batch (XCD), mt = y&7, nt = y>>3.
__global__ __launch_bounds__(512, 2) void k8_gemm_y(const unsigned short* __restrict__ pb,
    const unsigned short* __restrict__ ut, const unsigned short* __restrict__ q2b,
    const unsigned short* __restrict__ wpb, float* __restrict__ out) {
  __shared__ Smem8 sm;
  const int b = blockIdx.x;
  const int mt = blockIdx.y & 7;
  const int nt = blockIdx.y >> 3;
  const int m0 = mt * 256, n0 = nt * 256;
  const int NK1 = (mt + 1) * 4;                 // pb cols l < (mt+1)*256
  f32x4 acc[8][4]; acc_init8(acc);
  gemm8_core(
    [&](int r, int kt) {
      return (kt < NK1) ? pb + (size_t)b * LL * LL + (size_t)(m0 + r) * LL + kt * 64
                        : q2b + ((size_t)b * LL + m0 + r) * HH + (kt - NK1) * 64;
    },
    [&](int r, int kt) {
      return (kt < NK1) ? ut + (size_t)b * DD * LL + (size_t)(n0 + r) * LL + kt * 64
                        : wpb + (size_t)b * DD * HH + (size_t)(n0 + r) * HH + (kt - NK1) * 64;
    },
    NK1 + 16, &sm, acc);
  epi8(acc, [&](int rr, int cc, float av) {
    out[((size_t)b * LL + m0 + rr) * DD + (n0 + cc)] = av;
  });
}

// W_next = -Ut * K2t^T + ecl[b]*W_prev
__global__ __launch_bounds__(512, 2) void k8_gemm_wn(const unsigned short* __restrict__ ut,
    const unsigned short* __restrict__ k2t, const float* __restrict__ hid,
    const float* __restrict__ ecl, float* __restrict__ out2) {
  __shared__ Smem8 sm;
  const int b = blockIdx.x;
  const int mt = blockIdx.y & 3, nt = blockIdx.y >> 2;
  const int m0 = mt * 256, n0 = nt * 256;
  f32x4 acc[8][4]; acc_init8(acc);
  gemm8_core(
    [&](int r, int kt) { return ut + (size_t)b * DD * LL + (size_t)(m0 + r) * LL + kt * 64; },
    [&](int r, int kt) { return k2t + (size_t)b * HH * LL + (size_t)(n0 + r) * LL + kt * 64; },
    LL / 64, &sm, acc);
  const float eclb = ecl[b];
  epi8(acc, [&](int rr, int cc, float av) {
    const size_t gi = ((size_t)b * DD + (m0 + rr)) * HH + (n0 + cc);
    out2[gi] = -av + eclb * hid[gi];
  });
}

// ---------------- launcher ----------------

extern "C" void kernel_launch(void* const* d_in, const int* in_sizes, int n_in,
                              void* d_out, int out_size, void* d_ws, size_t ws_size,
                              hipStream_t stream) {
  (void)in_sizes; (void)n_in; (void)out_size; (void)ws_size;
  const float* x   = (const float*)d_in[0];
  const float* hid = (const float*)d_in[1];
  const float* lbl = (const float*)d_in[2];
  const float* wlr = (const float*)d_in[3];
  const float* blr = (const float*)d_in[4];
  const float* lbw = (const float*)d_in[5];
  const float* wwd = (const float*)d_in[6];
  const float* bwd = (const float*)d_in[7];
  const float* wq  = (const float*)d_in[8];
  const float* bq  = (const float*)d_in[9];
  const float* wk  = (const float*)d_in[10];
  const float* bk  = (const float*)d_in[11];
  const float* wv  = (const float*)d_in[12];
  const float* bv  = (const float*)d_in[13];
  float* out = (float*)d_out;

  char* w = (char*)d_ws;
  constexpr size_t SZ_XB  = (size_t)BL * DD * 2;
  constexpr size_t SZ_QB  = (size_t)BL * HH * 2;
  constexpr size_t SZ_KB  = (size_t)BL * HH * 2;
  constexpr size_t SZ_K2T = (size_t)BB * HH * LL * 2;
  constexpr size_t SZ_UT  = (size_t)BB * DD * LL * 2;
  constexpr size_t SZ_PB  = (size_t)BB * LL * LL * 2;
  constexpr size_t SZ_WT  = (size_t)DD * HH * 2;
  constexpr size_t SZ_WPB = (size_t)BB * DD * HH * 2;
  constexpr size_t SZ_V16 = (size_t)BL * 4;

  size_t off = 0;
  unsigned short* xb   = (unsigned short*)(w + off); off += SZ_XB;
  unsigned short* qb   = (unsigned short*)(w + off); off += SZ_QB;
  unsigned short* kb   = (unsigned short*)(w + off); off += SZ_KB;
  unsigned short* k2t  = (unsigned short*)(w + off); off += SZ_K2T;
  unsigned short* ut   = (unsigned short*)(w + off); off += SZ_UT;
  unsigned short* pb   = (unsigned short*)(w + off); off += SZ_PB;
  unsigned short* wqt  = (unsigned short*)(w + off); off += SZ_WT;
  unsigned short* wkt  = (unsigned short*)(w + off); off += SZ_WT;
  unsigned short* wvtn = (unsigned short*)(w + off); off += SZ_WT;
  unsigned short* wpb  = (unsigned short*)(w + off); off += SZ_WPB;
  float* lrlog = (float*)(w + off); off += SZ_V16;
  float* wdlog = (float*)(w + off); off += SZ_V16;
  float* lr    = (float*)(w + off); off += SZ_V16;
  float* c     = (float*)(w + off); off += SZ_V16;
  float* s     = (float*)(w + off); off += SZ_V16;
  float* ecl   = (float*)(w + off); off += 256;
  float* bias2 = (float*)(w + off); off += (size_t)BB * DD * 4;

  // w2t (16.8 MB) + wkr (2 MB) alias the pb region: dead before k8_gemm_p writes pb.
  unsigned short* w2t = pb;
  unsigned short* wkr = pb + (size_t)BB * DD * DD;

  // q2 scratch lives in d_out's W_next region; overwritten by k8_gemm_wn afterwards.
  unsigned short* q2b = (unsigned short*)(out + (size_t)BL * DD);
  float* out2 = out + (size_t)BL * DD;

  k_prep_x<<<dim3(BL / 4), 256, 0, stream>>>(x, wlr, wwd, xb, lrlog, wdlog);
  k_prep_w<<<dim3(4096, 1, 4), 256, 0, stream>>>(wq, wk, wv, wqt, wkt, wvtn, wkr);
  k_prep_h<<<dim3((unsigned)((size_t)BB * DD * HH / 1024)), 256, 0, stream>>>(hid, wpb);
  k_scan<<<dim3(BB), 256, 0, stream>>>(lrlog, wdlog, lbl, blr, lbw, bwd, lr, c, s, ecl);
  k_bias2<<<dim3(BB * DD / 4), 256, 0, stream>>>(wpb, bk, bv, bias2);

  k8_gemm_m2<<<dim3(8, 16), 512, 0, stream>>>(wpb, wkr, wvtn, w2t);
  k8_gemm_q<<<dim3(8, 32), 512, 0, stream>>>(xb, wqt, bq, c, qb, q2b);
  k8_gemm_k<<<dim3(8, 32), 512, 0, stream>>>(xb, wkt, bk, s, kb, k2t);
  k8_gemm_u<<<dim3(8, 32), 512, 0, stream>>>(xb, w2t, bias2, ut);
  k8_gemm_p<<<dim3(8, 36), 512, 0, stream>>>(qb, kb, lr, c, pb);
  k8_gemm_y<<<dim3(8, 32), 512, 0, stream>>>(pb, ut, q2b, wpb, out);
  k8_gemm_wn<<<dim3(8, 16), 512, 0, stream>>>(ut, k2t, hid, ecl, out2);
}